// Round 2
// baseline (359.730 us; speedup 1.0000x reference)
//
#include <hip/hip_runtime.h>
#include <hip/hip_bf16.h>

#define SS 8192
#define DD 2048
#define EE 64
#define CAP 128
// combine_weights size = SS*EE*CAP
#define SEC (67108864LL)

// ---------------------------------------------------------------------------
// Kernel 0: vectorized zero-fill of the 537 MB output.
// Replaces hipMemsetAsync (rocclr fillBufferAligned showed 4x write
// amplification: 2.147 GB written for a 537 MB buffer). Exactly
// 33,554,432 float4 stores + 1 scalar tail element.
// ---------------------------------------------------------------------------
__global__ __launch_bounds__(256) void k_fill(float* __restrict__ out) {
    const size_t n4 = (size_t)(2 * SEC) / 4;  // 33,554,432 float4 covers [0, 2*SEC)
    float4* __restrict__ out4 = (float4*)out;
    size_t i = (size_t)blockIdx.x * blockDim.x + threadIdx.x;
    const size_t stride = (size_t)gridDim.x * blockDim.x;
    const float4 z = make_float4(0.f, 0.f, 0.f, 0.f);
    for (; i < n4; i += stride) out4[i] = z;
    if (blockIdx.x == 0 && threadIdx.x == 0) out[2 * SEC] = 0.f;  // last element
}

// ---------------------------------------------------------------------------
// Kernel 1: fused gate GEMM + softmax + argmax.
// grid 512 blocks x 256 threads. Block handles 16 tokens.
// Wave pairs split D: waves {0,1} -> tokens 0..7 (halves d0/d1),
//                     waves {2,3} -> tokens 8..15.
// lane = expert (E=64 == wavefront). wg slices live in VGPRs; inner loop is
// pure v_fmac_f32.
// ---------------------------------------------------------------------------
__global__ __launch_bounds__(256) void k_gate(const float* __restrict__ x,
                                              const float* __restrict__ wg,
                                              int* __restrict__ idx_out,
                                              float* __restrict__ gval_out,
                                              float* __restrict__ gpart) {
    const int lane = threadIdx.x & 63;
    const int wv = __builtin_amdgcn_readfirstlane(threadIdx.x >> 6); // 0..3, SGPR
    const int tg = wv >> 1;   // token group within block
    const int dh = wv & 1;    // D half
    const int tokBase = blockIdx.x * 16 + tg * 8;
    const float* xp = x + (size_t)tokBase * DD + dh * 1024;

    float acc[8] = {0.f, 0.f, 0.f, 0.f, 0.f, 0.f, 0.f, 0.f};

    for (int d0 = 0; d0 < 1024; d0 += 16) {
        float w[16];
#pragma unroll
        for (int k = 0; k < 16; ++k)
            w[k] = wg[(size_t)(dh * 1024 + d0 + k) * EE + lane];
#pragma unroll
        for (int t = 0; t < 8; ++t) {
#pragma unroll
            for (int k = 0; k < 16; ++k)
                acc[t] = fmaf(xp[(size_t)t * DD + d0 + k], w[k], acc[t]);
        }
    }

    // combine the two D-halves through LDS
    __shared__ float part[4][8][64];
#pragma unroll
    for (int t = 0; t < 8; ++t) part[wv][t][lane] = acc[t];
    __syncthreads();

    __shared__ float gshare[2][64];
    if (dh == 0) {
        float gs = 0.f;
#pragma unroll
        for (int t = 0; t < 8; ++t) {
            float v = part[wv][t][lane] + part[wv + 1][t][lane];
            // argmax over lanes, first-index tie rule (matches jnp.argmax)
            float m = v;
            int mi = lane;
#pragma unroll
            for (int off = 1; off < 64; off <<= 1) {
                float ov = __shfl_xor(m, off);
                int oi = __shfl_xor(mi, off);
                if (ov > m || (ov == m && oi < mi)) { m = ov; mi = oi; }
            }
            float p = __expf(v - m);
            float s = p;
#pragma unroll
            for (int off = 1; off < 64; off <<= 1) s += __shfl_xor(s, off);
            gs += p / s;  // gates[tok][lane], accumulated per expert(=lane)
            if (lane == 0) {
                idx_out[tokBase + t] = mi;
                gval_out[tokBase + t] = 1.0f / s;  // gate value of argmax expert
            }
        }
        gshare[tg][lane] = gs;
    }
    __syncthreads();
    if (wv == 0) {
        gpart[(size_t)blockIdx.x * 64 + lane] = gshare[0][lane] + gshare[1][lane];
    }
}

// ---------------------------------------------------------------------------
// Kernel 2: per-expert rank (prefix count over token order) + scatter of
// combine_weights / dispatch_mask nonzeros. One block per expert.
// ---------------------------------------------------------------------------
__global__ __launch_bounds__(256) void k_scatter(const int* __restrict__ idx,
                                                 const float* __restrict__ gval,
                                                 float* __restrict__ out,
                                                 int* __restrict__ counts) {
    const int e = blockIdx.x;
    const int tid = threadIdx.x;
    const int lane = tid & 63;
    const int wv = tid >> 6;

    __shared__ int wtot[4];
    int running = 0;

    for (int s0 = 0; s0 < SS; s0 += 256) {
        const int s = s0 + tid;
        const bool flag = (idx[s] == e);
        unsigned long long mask = __ballot(flag);
        int excl = __popcll(mask & ((1ULL << lane) - 1ULL));
        int wt = __popcll(mask);
        if (lane == 0) wtot[wv] = wt;
        __syncthreads();
        int pre = 0;
#pragma unroll
        for (int w2 = 0; w2 < 4; ++w2)
            if (w2 < wv) pre += wtot[w2];
        const int blockTot = wtot[0] + wtot[1] + wtot[2] + wtot[3];
        const int rank = running + pre + excl;
        if (flag && rank < CAP) {
            const size_t o = (size_t)s * (EE * CAP) + (size_t)e * CAP + rank;
            out[1 + o] = gval[s];                 // combine_weights
            out[1 + (size_t)SEC + o] = 1.0f;      // dispatch_mask
        }
        running += blockTot;
        __syncthreads();
    }
    if (tid == 0) counts[e] = running;  // pre-drop count (ce uses pre-drop mask)
}

// ---------------------------------------------------------------------------
// Kernel 3: l_aux = E/S^2 * sum_e gatesum[e] * count[e]  -> d_out[0]
// ---------------------------------------------------------------------------
__global__ __launch_bounds__(256) void k_laux(const float* __restrict__ gpart,
                                              const int* __restrict__ counts,
                                              float* __restrict__ out) {
    const int lane = threadIdx.x & 63;
    const int stripe = threadIdx.x >> 6;
    float s = 0.f;
    for (int b = stripe; b < 512; b += 4) s += gpart[(size_t)b * 64 + lane];
    __shared__ float red[4][64];
    red[stripe][lane] = s;
    __syncthreads();
    if (threadIdx.x < 64) {
        float gsum = red[0][lane] + red[1][lane] + red[2][lane] + red[3][lane];
        float term = gsum * (float)counts[lane];
#pragma unroll
        for (int off = 1; off < 64; off <<= 1) term += __shfl_xor(term, off);
        if (lane == 0)
            out[0] = term * ((float)EE / ((float)SS * (float)SS));
    }
}

extern "C" void kernel_launch(void* const* d_in, const int* in_sizes, int n_in,
                              void* d_out, int out_size, void* d_ws, size_t ws_size,
                              hipStream_t stream) {
    const float* x = (const float*)d_in[0];
    const float* wg = (const float*)d_in[1];
    float* out = (float*)d_out;

    // workspace layout (floats): idx[8192] | gval[8192] | gpart[512*64] | counts[64]
    int* idxp = (int*)d_ws;
    float* gval = (float*)d_ws + SS;
    float* gpart = (float*)d_ws + 2 * SS;
    int* counts = (int*)d_ws + 2 * SS + 512 * 64;

    // zero the (almost entirely sparse) 537 MB output with coalesced float4
    hipLaunchKernelGGL(k_fill, dim3(2048), dim3(256), 0, stream, out);

    hipLaunchKernelGGL(k_gate, dim3(512), dim3(256), 0, stream, x, wg, idxp, gval, gpart);
    hipLaunchKernelGGL(k_scatter, dim3(64), dim3(256), 0, stream, idxp, gval, out, counts);
    hipLaunchKernelGGL(k_laux, dim3(1), dim3(256), 0, stream, gpart, counts, out);
}

// Round 4
// 224.115 us; speedup vs baseline: 1.6051x; 1.6051x over previous
//
#include <hip/hip_runtime.h>
#include <hip/hip_bf16.h>

#define SS 8192
#define DD 2048
#define EE 64
#define CAP 128
// combine_weights size = SS*EE*CAP
#define SEC (67108864LL)

typedef float floatx4 __attribute__((ext_vector_type(4)));

// ---------------------------------------------------------------------------
// Kernel 1: fused {zero-fill of 537 MB output} + {gate GEMM/softmax/argmax}.
// Blocks 0..511   : gate. Block b handles tokens 16b..16b+15.
//                   Waves {0,1} -> tokens 0..7 (D halves 0/1), {2,3} -> 8..15.
//                   lane = expert (E=64 == wavefront).
// Blocks 512..8703: fill. Each block zeroes one contiguous 64 KB chunk with
//                   nontemporal 16B stores (wave writes 1 KB/instr,
//                   block-contiguous -> page-local, full-line transactions).
// Gate compute (~2.15 GFLOP) hides under the memory-bound fill.
// ---------------------------------------------------------------------------
__global__ __launch_bounds__(256) void k_fill_gate(const float* __restrict__ x,
                                                   const float* __restrict__ wg,
                                                   float* __restrict__ out,
                                                   int* __restrict__ idx_out,
                                                   float* __restrict__ gval_out,
                                                   float* __restrict__ gpart) {
    if (blockIdx.x >= 512) {
        // ---- fill path: block owns 16B-elem range [fb*4096, (fb+1)*4096) ----
        const int fb = blockIdx.x - 512;  // 0..8191
        floatx4* __restrict__ out4 = (floatx4*)out;
        const size_t base = (size_t)fb * 4096 + threadIdx.x;
        const floatx4 z = {0.f, 0.f, 0.f, 0.f};
#pragma unroll
        for (int k = 0; k < 16; ++k)
            __builtin_nontemporal_store(z, &out4[base + (size_t)k * 256]);
        if (fb == 0 && threadIdx.x == 0) out[2 * SEC] = 0.f;  // tail element
        return;
    }

    // ---- gate path ----
    const int bid = blockIdx.x;  // 0..511
    const int lane = threadIdx.x & 63;
    const int wv = __builtin_amdgcn_readfirstlane(threadIdx.x >> 6); // 0..3
    const int tg = wv >> 1;   // token group within block
    const int dh = wv & 1;    // D half
    const int tokBase = bid * 16 + tg * 8;
    const float* xp = x + (size_t)tokBase * DD + dh * 1024;

    float acc[8] = {0.f, 0.f, 0.f, 0.f, 0.f, 0.f, 0.f, 0.f};

    for (int d0 = 0; d0 < 1024; d0 += 16) {
        float w[16];
#pragma unroll
        for (int k = 0; k < 16; ++k)
            w[k] = wg[(size_t)(dh * 1024 + d0 + k) * EE + lane];
#pragma unroll
        for (int t = 0; t < 8; ++t) {
#pragma unroll
            for (int k = 0; k < 16; ++k)
                acc[t] = fmaf(xp[(size_t)t * DD + d0 + k], w[k], acc[t]);
        }
    }

    // combine the two D-halves through LDS
    __shared__ float part[4][8][64];
#pragma unroll
    for (int t = 0; t < 8; ++t) part[wv][t][lane] = acc[t];
    __syncthreads();

    __shared__ float gshare[2][64];
    if (dh == 0) {
        float gs = 0.f;
#pragma unroll
        for (int t = 0; t < 8; ++t) {
            float v = part[wv][t][lane] + part[wv + 1][t][lane];
            // argmax over lanes, first-index tie rule (matches jnp.argmax)
            float m = v;
            int mi = lane;
#pragma unroll
            for (int off = 1; off < 64; off <<= 1) {
                float ov = __shfl_xor(m, off);
                int oi = __shfl_xor(mi, off);
                if (ov > m || (ov == m && oi < mi)) { m = ov; mi = oi; }
            }
            float p = __expf(v - m);
            float s = p;
#pragma unroll
            for (int off = 1; off < 64; off <<= 1) s += __shfl_xor(s, off);
            gs += p / s;  // gates[tok][lane], accumulated per expert(=lane)
            if (lane == 0) {
                idx_out[tokBase + t] = mi;
                gval_out[tokBase + t] = 1.0f / s;  // gate value of argmax expert
            }
        }
        gshare[tg][lane] = gs;
    }
    __syncthreads();
    if (wv == 0) {
        gpart[(size_t)bid * 64 + lane] = gshare[0][lane] + gshare[1][lane];
    }
}

// ---------------------------------------------------------------------------
// Kernel 2: per-expert rank (prefix count over token order) + scatter of
// combine_weights / dispatch_mask nonzeros. One block per expert.
// ---------------------------------------------------------------------------
__global__ __launch_bounds__(256) void k_scatter(const int* __restrict__ idx,
                                                 const float* __restrict__ gval,
                                                 float* __restrict__ out,
                                                 int* __restrict__ counts) {
    const int e = blockIdx.x;
    const int tid = threadIdx.x;
    const int lane = tid & 63;
    const int wv = tid >> 6;

    __shared__ int wtot[4];
    int running = 0;

    for (int s0 = 0; s0 < SS; s0 += 256) {
        const int s = s0 + tid;
        const bool flag = (idx[s] == e);
        unsigned long long mask = __ballot(flag);
        int excl = __popcll(mask & ((1ULL << lane) - 1ULL));
        int wt = __popcll(mask);
        if (lane == 0) wtot[wv] = wt;
        __syncthreads();
        int pre = 0;
#pragma unroll
        for (int w2 = 0; w2 < 4; ++w2)
            if (w2 < wv) pre += wtot[w2];
        const int blockTot = wtot[0] + wtot[1] + wtot[2] + wtot[3];
        const int rank = running + pre + excl;
        if (flag && rank < CAP) {
            const size_t o = (size_t)s * (EE * CAP) + (size_t)e * CAP + rank;
            out[1 + o] = gval[s];                 // combine_weights
            out[1 + (size_t)SEC + o] = 1.0f;      // dispatch_mask
        }
        running += blockTot;
        __syncthreads();
    }
    if (tid == 0) counts[e] = running;  // pre-drop count (ce uses pre-drop mask)
}

// ---------------------------------------------------------------------------
// Kernel 3: l_aux = E/S^2 * sum_e gatesum[e] * count[e]  -> d_out[0]
// 1024 threads to cut the latency-bound gpart reduction.
// ---------------------------------------------------------------------------
__global__ __launch_bounds__(1024) void k_laux(const float* __restrict__ gpart,
                                               const int* __restrict__ counts,
                                               float* __restrict__ out) {
    const int lane = threadIdx.x & 63;
    const int stripe = threadIdx.x >> 6;  // 0..15
    float s = 0.f;
    for (int b = stripe; b < 512; b += 16) s += gpart[(size_t)b * 64 + lane];
    __shared__ float red[16][64];
    red[stripe][lane] = s;
    __syncthreads();
    if (threadIdx.x < 64) {
        float gsum = 0.f;
#pragma unroll
        for (int r = 0; r < 16; ++r) gsum += red[r][lane];
        float term = gsum * (float)counts[lane];
#pragma unroll
        for (int off = 1; off < 64; off <<= 1) term += __shfl_xor(term, off);
        if (lane == 0)
            out[0] = term * ((float)EE / ((float)SS * (float)SS));
    }
}

extern "C" void kernel_launch(void* const* d_in, const int* in_sizes, int n_in,
                              void* d_out, int out_size, void* d_ws, size_t ws_size,
                              hipStream_t stream) {
    const float* x = (const float*)d_in[0];
    const float* wg = (const float*)d_in[1];
    float* out = (float*)d_out;

    // workspace layout (floats): idx[8192] | gval[8192] | gpart[512*64] | counts[64]
    int* idxp = (int*)d_ws;
    float* gval = (float*)d_ws + SS;
    float* gpart = (float*)d_ws + 2 * SS;
    int* counts = (int*)d_ws + 2 * SS + 512 * 64;

    // fused fill (blocks 512..8703) + gate (blocks 0..511)
    hipLaunchKernelGGL(k_fill_gate, dim3(8704), dim3(256), 0, stream,
                       x, wg, out, idxp, gval, gpart);
    hipLaunchKernelGGL(k_scatter, dim3(64), dim3(256), 0, stream, idxp, gval, out, counts);
    hipLaunchKernelGGL(k_laux, dim3(1), dim3(1024), 0, stream, gpart, counts, out);
}

// Round 5
// 161.960 us; speedup vs baseline: 2.2211x; 1.3838x over previous
//
#include <hip/hip_runtime.h>
#include <hip/hip_bf16.h>

#define SS 8192
#define DD 2048
#define EE 64
#define CAP 128
// combine_weights size = SS*EE*CAP
#define SEC (67108864LL)

typedef float floatx4 __attribute__((ext_vector_type(4)));

__device__ __forceinline__ float bcast(float v, int lane) {
    return __builtin_bit_cast(float,
        __builtin_amdgcn_readlane(__builtin_bit_cast(int, v), lane));
}

// ---------------------------------------------------------------------------
// Kernel 1: fused {zero-fill of 537 MB output} + {gate GEMM/softmax/argmax}.
// Blocks 0..511   : gate. Block b handles tokens 16b..16b+15.
//                   Waves {0,1} -> tokens 0..7 (D halves 0/1), {2,3} -> 8..15.
//                   lane = expert (E=64 == wavefront).
//                   x is loaded COALESCED into VGPRs (xv[t] = x[t][k0+lane])
//                   and broadcast per-k via v_readlane -> v_fmac. This removes
//                   the ~8K per-lane broadcast VMEM loads/wave that made the
//                   r4 gate VMEM-issue-bound (~200us).
// Blocks 512..8703: fill. Each block zeroes one contiguous 64 KB chunk with
//                   nontemporal 16B stores.
// Gate compute overlaps the memory-bound fill (VALU vs VMEM-write pipes).
// ---------------------------------------------------------------------------
__global__ __launch_bounds__(256) void k_fill_gate(const float* __restrict__ x,
                                                   const float* __restrict__ wg,
                                                   float* __restrict__ out,
                                                   int* __restrict__ idx_out,
                                                   float* __restrict__ gval_out,
                                                   float* __restrict__ gpart) {
    if (blockIdx.x >= 512) {
        // ---- fill path: block owns 16B-elem range [fb*4096, (fb+1)*4096) ----
        const int fb = blockIdx.x - 512;  // 0..8191
        floatx4* __restrict__ out4 = (floatx4*)out;
        const size_t base = (size_t)fb * 4096 + threadIdx.x;
        const floatx4 z = {0.f, 0.f, 0.f, 0.f};
#pragma unroll
        for (int k = 0; k < 16; ++k)
            __builtin_nontemporal_store(z, &out4[base + (size_t)k * 256]);
        if (fb == 0 && threadIdx.x == 0) out[2 * SEC] = 0.f;  // tail element
        return;
    }

    // ---- gate path ----
    const int bid = blockIdx.x;  // 0..511
    const int lane = threadIdx.x & 63;
    const int wv = __builtin_amdgcn_readfirstlane(threadIdx.x >> 6); // 0..3
    const int tg = wv >> 1;   // token group within block
    const int dh = wv & 1;    // D half
    const int tokBase = bid * 16 + tg * 8;
    const float* xp = x + (size_t)tokBase * DD + dh * 1024;
    const float* wp = wg + (size_t)dh * 1024 * EE + lane;

    float acc[8] = {0.f, 0.f, 0.f, 0.f, 0.f, 0.f, 0.f, 0.f};

    // 16 batches of 64 k-values each (covers this wave's 1024-deep D half)
    for (int b = 0; b < 16; ++b) {
        float xv[8];
#pragma unroll
        for (int t = 0; t < 8; ++t)
            xv[t] = xp[(size_t)t * DD + b * 64 + lane];  // coalesced 256B

#pragma unroll
        for (int g = 0; g < 4; ++g) {
            float w[16];
#pragma unroll
            for (int j = 0; j < 16; ++j)
                w[j] = wp[(size_t)(b * 64 + g * 16 + j) * EE];  // coalesced
#pragma unroll
            for (int j = 0; j < 16; ++j) {
#pragma unroll
                for (int t = 0; t < 8; ++t)
                    acc[t] = fmaf(bcast(xv[t], g * 16 + j), w[j], acc[t]);
            }
        }
    }

    // combine the two D-halves through LDS
    __shared__ float part[4][8][64];
#pragma unroll
    for (int t = 0; t < 8; ++t) part[wv][t][lane] = acc[t];
    __syncthreads();

    __shared__ float gshare[2][64];
    if (dh == 0) {
        float gs = 0.f;
#pragma unroll
        for (int t = 0; t < 8; ++t) {
            float v = part[wv][t][lane] + part[wv + 1][t][lane];
            // argmax over lanes, first-index tie rule (matches jnp.argmax)
            float m = v;
            int mi = lane;
#pragma unroll
            for (int off = 1; off < 64; off <<= 1) {
                float ov = __shfl_xor(m, off);
                int oi = __shfl_xor(mi, off);
                if (ov > m || (ov == m && oi < mi)) { m = ov; mi = oi; }
            }
            float p = __expf(v - m);
            float s = p;
#pragma unroll
            for (int off = 1; off < 64; off <<= 1) s += __shfl_xor(s, off);
            gs += p / s;  // gates[tok][lane], accumulated per expert(=lane)
            if (lane == 0) {
                idx_out[tokBase + t] = mi;
                gval_out[tokBase + t] = 1.0f / s;  // gate value of argmax expert
            }
        }
        gshare[tg][lane] = gs;
    }
    __syncthreads();
    if (wv == 0) {
        gpart[(size_t)bid * 64 + lane] = gshare[0][lane] + gshare[1][lane];
    }
}

// ---------------------------------------------------------------------------
// Kernel 2: per-expert rank (prefix count over token order) + scatter of
// combine_weights / dispatch_mask nonzeros. One block per expert.
// ---------------------------------------------------------------------------
__global__ __launch_bounds__(256) void k_scatter(const int* __restrict__ idx,
                                                 const float* __restrict__ gval,
                                                 float* __restrict__ out,
                                                 int* __restrict__ counts) {
    const int e = blockIdx.x;
    const int tid = threadIdx.x;
    const int lane = tid & 63;
    const int wv = tid >> 6;

    __shared__ int wtot[4];
    int running = 0;

    for (int s0 = 0; s0 < SS; s0 += 256) {
        const int s = s0 + tid;
        const bool flag = (idx[s] == e);
        unsigned long long mask = __ballot(flag);
        int excl = __popcll(mask & ((1ULL << lane) - 1ULL));
        int wt = __popcll(mask);
        if (lane == 0) wtot[wv] = wt;
        __syncthreads();
        int pre = 0;
#pragma unroll
        for (int w2 = 0; w2 < 4; ++w2)
            if (w2 < wv) pre += wtot[w2];
        const int blockTot = wtot[0] + wtot[1] + wtot[2] + wtot[3];
        const int rank = running + pre + excl;
        if (flag && rank < CAP) {
            const size_t o = (size_t)s * (EE * CAP) + (size_t)e * CAP + rank;
            out[1 + o] = gval[s];                 // combine_weights
            out[1 + (size_t)SEC + o] = 1.0f;      // dispatch_mask
        }
        running += blockTot;
        __syncthreads();
    }
    if (tid == 0) counts[e] = running;  // pre-drop count (ce uses pre-drop mask)
}

// ---------------------------------------------------------------------------
// Kernel 3: l_aux = E/S^2 * sum_e gatesum[e] * count[e]  -> d_out[0]
// ---------------------------------------------------------------------------
__global__ __launch_bounds__(1024) void k_laux(const float* __restrict__ gpart,
                                               const int* __restrict__ counts,
                                               float* __restrict__ out) {
    const int lane = threadIdx.x & 63;
    const int stripe = threadIdx.x >> 6;  // 0..15
    float s = 0.f;
    for (int b = stripe; b < 512; b += 16) s += gpart[(size_t)b * 64 + lane];
    __shared__ float red[16][64];
    red[stripe][lane] = s;
    __syncthreads();
    if (threadIdx.x < 64) {
        float gsum = 0.f;
#pragma unroll
        for (int r = 0; r < 16; ++r) gsum += red[r][lane];
        float term = gsum * (float)counts[lane];
#pragma unroll
        for (int off = 1; off < 64; off <<= 1) term += __shfl_xor(term, off);
        if (lane == 0)
            out[0] = term * ((float)EE / ((float)SS * (float)SS));
    }
}

extern "C" void kernel_launch(void* const* d_in, const int* in_sizes, int n_in,
                              void* d_out, int out_size, void* d_ws, size_t ws_size,
                              hipStream_t stream) {
    const float* x = (const float*)d_in[0];
    const float* wg = (const float*)d_in[1];
    float* out = (float*)d_out;

    // workspace layout (floats): idx[8192] | gval[8192] | gpart[512*64] | counts[64]
    int* idxp = (int*)d_ws;
    float* gval = (float*)d_ws + SS;
    float* gpart = (float*)d_ws + 2 * SS;
    int* counts = (int*)d_ws + 2 * SS + 512 * 64;

    // fused fill (blocks 512..8703) + gate (blocks 0..511)
    hipLaunchKernelGGL(k_fill_gate, dim3(8704), dim3(256), 0, stream,
                       x, wg, out, idxp, gval, gpart);
    hipLaunchKernelGGL(k_scatter, dim3(64), dim3(256), 0, stream, idxp, gval, out, counts);
    hipLaunchKernelGGL(k_laux, dim3(1), dim3(1024), 0, stream, gpart, counts, out);
}